// Round 6
// baseline (2121.747 us; speedup 1.0000x reference)
//
#include <hip/hip_runtime.h>
#include <stdint.h>

// JAX jax_threefry_partitionable=True semantics (verified exact, rounds 1-5).
// Round-6: FUSE scan and sim into one kernel. Block 0 = persistent 29-step sim (one CU);
// blocks 1..29000 scan H rows and publish them with release-atomics on per-step counters.
// Sim consumes step t as soon as its 1000 rows are ready (acquire spin + agent-relaxed
// atomic loads of edge data). This overlaps the ~230us HBM-bound scan with the ~150us
// latency-bound sim instead of running them serially. R5's trace+expand reverted (it
// regressed: sim was latency-bound, not write-bound).
constexpr int NN = 10000;          // nodes
constexpr int EE = 1000;           // hyperedges
constexpr int TT = 30;             // output rows
constexpr int TS = TT - 1;         // simulated steps
constexpr int ROW = NN * 3;        // floats per output row
constexpr int S_OFF = TT * ROW;    // state section offset in d_out
constexpr int CAP_E = 48;          // max nodes per edge (P(>=48) ~ 1e-30)
constexpr int WPR = CAP_E / 2;     // packed uint32 words per edge row
constexpr int SIMT = 1024;         // sim block threads (16 waves)
constexpr int NPT  = 10;           // nodes per thread (1024*10 >= 10000)

// ---- Threefry-2x32, 20 rounds (exact JAX semantics), host+device ----
__host__ __device__ inline void tf2x32(uint32_t k0, uint32_t k1,
                                       uint32_t x0, uint32_t x1,
                                       uint32_t &o0, uint32_t &o1) {
  uint32_t ks2 = k0 ^ k1 ^ 0x1BD11BDAu;
  x0 += k0; x1 += k1;
#define TFR(r) do { x0 += x1; x1 = (x1 << (r)) | (x1 >> (32 - (r))); x1 ^= x0; } while (0)
  TFR(13); TFR(15); TFR(26); TFR(6);
  x0 += k1;  x1 += ks2 + 1u;
  TFR(17); TFR(29); TFR(16); TFR(24);
  x0 += ks2; x1 += k0 + 2u;
  TFR(13); TFR(15); TFR(26); TFR(6);
  x0 += k0;  x1 += k1 + 3u;
  TFR(17); TFR(29); TFR(16); TFR(24);
  x0 += k1;  x1 += ks2 + 4u;
  TFR(13); TFR(15); TFR(26); TFR(6);
  x0 += ks2; x1 += k0 + 5u;
#undef TFR
  o0 = x0; o1 = x1;
}

__device__ inline float bits_to_uniform(uint32_t bits) {
  float f = __uint_as_float((bits >> 9) | 0x3F800000u) - 1.0f;
  return f < 0.f ? 0.f : f;
}

struct StepKeys { uint32_t k1a[TS], k1b[TS], k2a[TS], k2b[TS]; };

// precompute ALL uniforms (state-independent); block (0,0) also zeroes the step counters
__global__ void k_rand(float* __restrict__ u1, float* __restrict__ u2,
                       unsigned* __restrict__ cnt, StepKeys keys) {
  int t = blockIdx.y;
  int n = blockIdx.x * blockDim.x + threadIdx.x;
  if (blockIdx.x == 0 && blockIdx.y == 0 && threadIdx.x < TS) cnt[threadIdx.x] = 0u;
  if (n >= NN) return;
  uint32_t a, b;
  tf2x32(keys.k1a[t], keys.k1b[t], 0u, (uint32_t)n, a, b);
  u1[t * NN + n] = bits_to_uniform(a ^ b);
  tf2x32(keys.k2a[t], keys.k2b[t], 0u, (uint32_t)n, a, b);
  u2[t * NN + n] = bits_to_uniform(a ^ b);
}

// ---- fused: block 0 = sim; blocks 1..TS*EE = scan one (t,e) row of H each ----
__global__ __launch_bounds__(SIMT, 1)
void k_fused(const float* __restrict__ H,
             int* __restrict__ edge_cnt, uint32_t* __restrict__ edge_words,
             unsigned* __restrict__ cnt,
             const float* __restrict__ x,
             const float* __restrict__ u1, const float* __restrict__ u2,
             const float* __restrict__ beta, const float* __restrict__ gamma_,
             float* __restrict__ out) {
  const int tid = threadIdx.x;

  if (blockIdx.x > 0) {
    // ---------------- scan role ----------------
    const int row = blockIdx.x - 1;  // t*EE + e
    const int t = row / EE;
    const int e = row - t * EE;
    __shared__ int scnt;
    __shared__ uint16_t list[CAP_E];
    if (tid == 0) scnt = 0;
    __syncthreads();
    const float4* hrow = reinterpret_cast<const float4*>(H + (size_t)row * NN);
    for (int i = tid; i < NN / 4; i += SIMT) {
      float4 v = hrow[i];
      int b4 = i * 4;
      if (v.x != 0.f) { int p = atomicAdd(&scnt, 1); if (p < CAP_E) list[p] = (uint16_t)(b4 + 0); }
      if (v.y != 0.f) { int p = atomicAdd(&scnt, 1); if (p < CAP_E) list[p] = (uint16_t)(b4 + 1); }
      if (v.z != 0.f) { int p = atomicAdd(&scnt, 1); if (p < CAP_E) list[p] = (uint16_t)(b4 + 2); }
      if (v.w != 0.f) { int p = atomicAdd(&scnt, 1); if (p < CAP_E) list[p] = (uint16_t)(b4 + 3); }
    }
    __syncthreads();
    int c = scnt < CAP_E ? scnt : CAP_E;
    if (tid == 0) edge_cnt[row] = c;
    int words = (c + 1) >> 1;
    if (tid < words) {
      uint32_t lo = list[2 * tid];
      uint32_t hi = (2 * tid + 1 < c) ? (uint32_t)list[2 * tid + 1] : 0xFFFFu;
      // transposed-by-word layout: coalesced for sim's per-edge-thread reads
      edge_words[((size_t)t * WPR + tid) * EE + e] = lo | (hi << 16);
    }
    __syncthreads();  // all stores drained (vmcnt(0) before barrier)
    if (tid == 0)     // release: write back this XCD's L2, then publish
      __hip_atomic_fetch_add(&cnt[t], 1u, __ATOMIC_RELEASE, __HIP_MEMORY_SCOPE_AGENT);
    return;
  }

  // ---------------- sim role (block 0, one CU) ----------------
  __shared__ uint8_t s_st[NN];   // 10 KB: state code 0=S 1=I 2=R
  __shared__ int nv[NN];         // 40 KB: per-node two-hop infected count (exact ints)

  float p0[NPT], p1[NPT], p2[NPT], bet[NPT], gam[NPT];
#pragma unroll
  for (int k = 0; k < NPT; ++k) {
    int n = tid + k * SIMT;
    if (n < NN) {
      float x0 = x[n * 3 + 0], x1 = x[n * 3 + 1], x2 = x[n * 3 + 2];
      p0[k] = x0; p1[k] = x1; p2[k] = x2;
      s_st[n] = (x1 == 1.f) ? 1 : ((x0 == 1.f) ? 0 : 2);
      nv[n] = 0;
      bet[k] = beta[n]; gam[k] = gamma_[n];
      // row 0 of both output sections = x
      out[n * 3 + 0] = x0; out[n * 3 + 1] = x1; out[n * 3 + 2] = x2;
      out[S_OFF + n * 3 + 0] = x0; out[S_OFF + n * 3 + 1] = x1; out[S_OFF + n * 3 + 2] = x2;
    }
  }
  __syncthreads();

  for (int t = 0; t < TS; ++t) {
    // preload this step's uniforms into registers (overlaps with the spin below)
    float u1r[NPT], u2r[NPT];
#pragma unroll
    for (int k = 0; k < NPT; ++k) {
      int n = tid + k * SIMT;
      if (n < NN) { u1r[k] = u1[(size_t)t * NN + n]; u2r[k] = u2[(size_t)t * NN + n]; }
    }
    // wait for all 1000 scan rows of step t (acquire pairs with scan's release)
    if (tid == 0) {
      while (__hip_atomic_load(&cnt[t], __ATOMIC_ACQUIRE, __HIP_MEMORY_SCOPE_AGENT)
             < (unsigned)EE) {
        __builtin_amdgcn_s_sleep(16);
      }
    }
    __syncthreads();  // barrier A: publishes scan data + prev step's s_st/nv-zero

    // edge phase: s = #infected members; scatter s into members' nv (skip if s==0)
    if (tid < EE) {
      int ec = __hip_atomic_load(&edge_cnt[t * EE + tid], __ATOMIC_RELAXED,
                                 __HIP_MEMORY_SCOPE_AGENT);
      if (ec > CAP_E) ec = CAP_E;
      int words = (ec + 1) >> 1;
      const uint32_t* wb = edge_words + (size_t)t * WPR * EE + tid;
      int s = 0;
      for (int mw = 0; mw < words; ++mw) {
        uint32_t w = __hip_atomic_load(&wb[(size_t)mw * EE], __ATOMIC_RELAXED,
                                       __HIP_MEMORY_SCOPE_AGENT);
        s += (s_st[w & 0xFFFFu] == 1) ? 1 : 0;
        uint32_t hi = w >> 16;
        if (hi != 0xFFFFu) s += (s_st[hi] == 1) ? 1 : 0;
      }
      if (s > 0) {  // adding 0 is a no-op: exactness unaffected
        for (int mw = 0; mw < words; ++mw) {
          uint32_t w = __hip_atomic_load(&wb[(size_t)mw * EE], __ATOMIC_RELAXED,
                                         __HIP_MEMORY_SCOPE_AGENT);
          atomicAdd(&nv[w & 0xFFFFu], s);
          uint32_t hi = w >> 16;
          if (hi != 0xFFFFu) atomicAdd(&nv[(int)hi], s);
        }
      }
    }
    __syncthreads();  // barrier B: nv complete

    // node phase: advance p in regs, draw transitions, write output rows, zero nv
    float* po = out + (size_t)(t + 1) * ROW;
    float* so = out + S_OFF + (size_t)(t + 1) * ROW;
#pragma unroll
    for (int k = 0; k < NPT; ++k) {
      int n = tid + k * SIMT;
      if (n < NN) {
        int st = s_st[n];
        int v = nv[n];
        nv[n] = 0;  // zero for next step (protected by next barrier A)
        float s1 = (st == 1) ? 1.f : 0.f;
        float new_cases = __fmul_rn(bet[k], (float)v);
        float new_rec   = __fmul_rn(gam[k], s1);
        float q0 = fminf(1.f, fmaxf(0.f, __fsub_rn(p0[k], new_cases)));
        float q1 = fminf(1.f, fmaxf(0.f, __fsub_rn(__fadd_rn(p1[k], new_cases), new_rec)));
        float q2 = fminf(1.f, fmaxf(0.f, __fadd_rn(p2[k], new_rec)));
        p0[k] = q0; p1[k] = q1; p2[k] = q2;

        bool was_S  = (st == 0);
        bool was_I  = (st == 1);
        bool s_to_I = was_S && (u1r[k] < q1);
        bool i_event = was_I && (u1r[k] < q2);
        bool u2lt   = (u2r[k] < 0.5f);
        bool i_to_R = i_event && u2lt;
        bool i_to_S = i_event && !u2lt;
        bool new_S = (was_S && !s_to_I) || i_to_S;
        bool new_I = s_to_I || (was_I && !i_event);
        bool new_R = (!was_S && !was_I) || i_to_R;

        po[n * 3 + 0] = q0; po[n * 3 + 1] = q1; po[n * 3 + 2] = q2;
        so[n * 3 + 0] = new_S ? 1.f : 0.f;
        so[n * 3 + 1] = new_I ? 1.f : 0.f;
        so[n * 3 + 2] = new_R ? 1.f : 0.f;
        s_st[n] = new_I ? 1 : (new_S ? 0 : 2);
      }
    }
    // next iteration's barrier A orders s_st/nv against the next edge phase
  }
}

extern "C" void kernel_launch(void* const* d_in, const int* in_sizes, int n_in,
                              void* d_out, int out_size, void* d_ws, size_t ws_size,
                              hipStream_t stream) {
  const float* x      = (const float*)d_in[0];
  const float* H      = (const float*)d_in[1];
  const float* beta   = (const float*)d_in[2];
  const float* gamma_ = (const float*)d_in[3];
  float* out = (float*)d_out;

  // key chain: key0 = jax.random.key(42) = (0,42); split(key,3) partitionable:
  // subkey i = threefry(key, (0,i)); carry = subkey 0.
  StepKeys keys;
  uint32_t key0 = 0u, key1 = 42u;
  for (int t = 0; t < TS; ++t) {
    uint32_t a0, b0, a1, b1, a2, b2;
    tf2x32(key0, key1, 0u, 0u, a0, b0);
    tf2x32(key0, key1, 0u, 1u, a1, b1);
    tf2x32(key0, key1, 0u, 2u, a2, b2);
    keys.k1a[t] = a1; keys.k1b[t] = b1; keys.k2a[t] = a2; keys.k2b[t] = b2;
    key0 = a0; key1 = b0;
  }

  // workspace layout (~5.2 MB)
  size_t off = 0;
  auto take = [&](size_t bytes) { size_t o = off; off += (bytes + 255) & ~(size_t)255; return o; };
  size_t o_ec = take((size_t)TS * EE * sizeof(int));
  size_t o_ew = take((size_t)TS * WPR * EE * sizeof(uint32_t));
  size_t o_u1 = take((size_t)TS * NN * sizeof(float));
  size_t o_u2 = take((size_t)TS * NN * sizeof(float));
  size_t o_ct = take((size_t)TS * sizeof(unsigned));

  int*      edge_cnt   = (int*)((char*)d_ws + o_ec);
  uint32_t* edge_words = (uint32_t*)((char*)d_ws + o_ew);
  float*    u1         = (float*)((char*)d_ws + o_u1);
  float*    u2         = (float*)((char*)d_ws + o_u2);
  unsigned* cnt        = (unsigned*)((char*)d_ws + o_ct);

  k_rand<<<dim3((NN + 255) / 256, TS), 256, 0, stream>>>(u1, u2, cnt, keys);
  k_fused<<<1 + TS * EE, SIMT, 0, stream>>>(H, edge_cnt, edge_words, cnt,
                                            x, u1, u2, beta, gamma_, out);
}

// Round 7
// 1753.579 us; speedup vs baseline: 1.2100x; 1.2100x over previous
//
#include <hip/hip_runtime.h>
#include <stdint.h>

// JAX jax_threefry_partitionable=True semantics (verified exact, rounds 1-6).
// Round-7: revert to R4 skeleton (separate full-chip k_scan + single-CU k_sim writing
// output rows directly; R6's fused producer/consumer regressed 2x - agent-scope
// release/acquire + 50KB LDS union killed scan occupancy and L2). Sim micro-opts:
//   (1) LDS-only barriers (s_waitcnt lgkmcnt(0); s_barrier) so the 240 KB/step output
//       stores drain in the background instead of stalling every __syncthreads,
//   (2) u1/u2 preloaded into registers at loop top (latency hidden behind edge phase),
//   (3) sentinel-padded packed edge words with unconditional 8-word prefetch (one
//       memory latency instead of a 5-deep dependent loop),
//   (4) skip nv-scatter for edges with 0 infected; nv zeroing folded into node phase.
constexpr int NN = 10000;          // nodes
constexpr int EE = 1000;           // hyperedges
constexpr int TT = 30;             // output rows
constexpr int TS = TT - 1;         // simulated steps
constexpr int ROW = NN * 3;        // floats per output row
constexpr int S_OFF = TT * ROW;    // state section offset in d_out
constexpr int CAP_E = 48;          // max nodes per edge (P(>=48) ~ 1e-30)
constexpr int WPR = CAP_E / 2;     // packed uint32 words per edge row
constexpr int PREW = 8;            // words prefetched unconditionally (covers ec<=16, ~97%)
constexpr int SIMT = 1024;         // sim block threads (16 waves on one CU)
constexpr int NPT  = 10;           // nodes per thread (1024*10 >= 10000)

// ---- Threefry-2x32, 20 rounds (exact JAX semantics), host+device ----
__host__ __device__ inline void tf2x32(uint32_t k0, uint32_t k1,
                                       uint32_t x0, uint32_t x1,
                                       uint32_t &o0, uint32_t &o1) {
  uint32_t ks2 = k0 ^ k1 ^ 0x1BD11BDAu;
  x0 += k0; x1 += k1;
#define TFR(r) do { x0 += x1; x1 = (x1 << (r)) | (x1 >> (32 - (r))); x1 ^= x0; } while (0)
  TFR(13); TFR(15); TFR(26); TFR(6);
  x0 += k1;  x1 += ks2 + 1u;
  TFR(17); TFR(29); TFR(16); TFR(24);
  x0 += ks2; x1 += k0 + 2u;
  TFR(13); TFR(15); TFR(26); TFR(6);
  x0 += k0;  x1 += k1 + 3u;
  TFR(17); TFR(29); TFR(16); TFR(24);
  x0 += k1;  x1 += ks2 + 4u;
  TFR(13); TFR(15); TFR(26); TFR(6);
  x0 += ks2; x1 += k0 + 5u;
#undef TFR
  o0 = x0; o1 = x1;
}

__device__ inline float bits_to_uniform(uint32_t bits) {
  float f = __uint_as_float((bits >> 9) | 0x3F800000u) - 1.0f;
  return f < 0.f ? 0.f : f;
}

struct StepKeys { uint32_t k1a[TS], k1b[TS], k2a[TS], k2b[TS]; };

// LDS-only barrier: orders LDS ops across the block WITHOUT draining global stores
// (vmcnt). Safe here because cross-phase dependencies in k_sim are all through LDS;
// global output stores are fire-and-forget and drain at s_endpgm.
__device__ inline void bar_lds() {
  asm volatile("s_waitcnt lgkmcnt(0)\n\ts_barrier" ::: "memory");
}

// precompute ALL uniforms (state-independent): u1[t][n], u2[t][n]
__global__ void k_rand(float* __restrict__ u1, float* __restrict__ u2, StepKeys keys) {
  int t = blockIdx.y;
  int n = blockIdx.x * blockDim.x + threadIdx.x;
  if (n >= NN) return;
  uint32_t a, b;
  tf2x32(keys.k1a[t], keys.k1b[t], 0u, (uint32_t)n, a, b);
  u1[t * NN + n] = bits_to_uniform(a ^ b);
  tf2x32(keys.k2a[t], keys.k2b[t], 0u, (uint32_t)n, a, b);
  u2[t * NN + n] = bits_to_uniform(a ^ b);
}

// edge->node lists as sentinel-padded packed words, transposed by word index:
// edge_words[(t*WPR + j)*EE + e] = members 2j,2j+1 of edge e (0xFFFF = empty slot).
// Words j < max(words, PREW) are always written (sentinel-padded) so sim can
// unconditionally prefetch PREW words.
__global__ void k_scan(const float* __restrict__ H, int* __restrict__ edge_cnt,
                       uint32_t* __restrict__ edge_words) {
  const int row = blockIdx.x;  // t*EE + e
  const int t = row / EE;
  const int e = row - t * EE;
  __shared__ int cnt;
  __shared__ uint16_t list[CAP_E];
  if (threadIdx.x == 0) cnt = 0;
  __syncthreads();
  const float4* hrow = reinterpret_cast<const float4*>(H + (size_t)row * NN);
  for (int i = threadIdx.x; i < NN / 4; i += blockDim.x) {
    float4 v = hrow[i];
    int b4 = i * 4;
    if (v.x != 0.f) { int p = atomicAdd(&cnt, 1); if (p < CAP_E) list[p] = (uint16_t)(b4 + 0); }
    if (v.y != 0.f) { int p = atomicAdd(&cnt, 1); if (p < CAP_E) list[p] = (uint16_t)(b4 + 1); }
    if (v.z != 0.f) { int p = atomicAdd(&cnt, 1); if (p < CAP_E) list[p] = (uint16_t)(b4 + 2); }
    if (v.w != 0.f) { int p = atomicAdd(&cnt, 1); if (p < CAP_E) list[p] = (uint16_t)(b4 + 3); }
  }
  __syncthreads();
  int c = cnt < CAP_E ? cnt : CAP_E;
  if (threadIdx.x == 0) edge_cnt[row] = c;
  int words = (c + 1) >> 1;
  int wmax = words > PREW ? words : PREW;
  if ((int)threadIdx.x < wmax) {
    int j = threadIdx.x;
    uint32_t lo = (2 * j     < c) ? (uint32_t)list[2 * j]     : 0xFFFFu;
    uint32_t hi = (2 * j + 1 < c) ? (uint32_t)list[2 * j + 1] : 0xFFFFu;
    edge_words[((size_t)t * WPR + j) * EE + e] = lo | (hi << 16);
  }
}

// ---- all 29 steps, one workgroup; p in regs, s in LDS, nv via LDS int atomics ----
__global__ __launch_bounds__(SIMT, 4)
void k_sim(float* __restrict__ out, const float* __restrict__ x,
           const int* __restrict__ edge_cnt, const uint32_t* __restrict__ edge_words,
           const float* __restrict__ u1, const float* __restrict__ u2,
           const float* __restrict__ beta, const float* __restrict__ gamma_) {
  __shared__ uint8_t s_st[NN];   // 10 KB: state code 0=S 1=I 2=R
  __shared__ int nv[NN];         // 40 KB: per-node two-hop infected count (exact ints)
  const int tid = threadIdx.x;

  float p0[NPT], p1[NPT], p2[NPT], bet[NPT], gam[NPT];
#pragma unroll
  for (int k = 0; k < NPT; ++k) {
    int n = tid + k * SIMT;
    if (n < NN) {
      float x0 = x[n * 3 + 0], x1 = x[n * 3 + 1], x2 = x[n * 3 + 2];
      p0[k] = x0; p1[k] = x1; p2[k] = x2;
      s_st[n] = (x1 == 1.f) ? 1 : ((x0 == 1.f) ? 0 : 2);
      nv[n] = 0;
      bet[k] = beta[n]; gam[k] = gamma_[n];
      // row 0 of both output sections = x (fire-and-forget)
      out[n * 3 + 0] = x0; out[n * 3 + 1] = x1; out[n * 3 + 2] = x2;
      out[S_OFF + n * 3 + 0] = x0; out[S_OFF + n * 3 + 1] = x1; out[S_OFF + n * 3 + 2] = x2;
    }
  }
  bar_lds();

  for (int t = 0; t < TS; ++t) {
    // preload this step's uniforms (consumed in node phase; latency hidden by edge phase)
    float u1r[NPT], u2r[NPT];
#pragma unroll
    for (int k = 0; k < NPT; ++k) {
      int n = tid + k * SIMT;
      if (n < NN) { u1r[k] = u1[(size_t)t * NN + n]; u2r[k] = u2[(size_t)t * NN + n]; }
    }

    // edge phase: s = #infected members; scatter s into members' nv (skip if s==0)
    if (tid < EE) {
      const uint32_t* wb = edge_words + (size_t)t * WPR * EE + tid;
      int ec = edge_cnt[t * EE + tid]; if (ec > CAP_E) ec = CAP_E;
      uint32_t w[PREW];
#pragma unroll
      for (int j = 0; j < PREW; ++j) w[j] = wb[(size_t)j * EE];  // independent, one latency
      int words = (ec + 1) >> 1;
      int s = 0;
#pragma unroll
      for (int j = 0; j < PREW; ++j) {
        uint32_t lo = w[j] & 0xFFFFu, hi = w[j] >> 16;
        if (lo != 0xFFFFu) s += (s_st[lo] == 1) ? 1 : 0;
        if (hi != 0xFFFFu) s += (s_st[hi] == 1) ? 1 : 0;
      }
      for (int j = PREW; j < words; ++j) {  // rare (ec > 16, ~3% of edges)
        uint32_t ww = wb[(size_t)j * EE];
        uint32_t lo = ww & 0xFFFFu, hi = ww >> 16;
        if (lo != 0xFFFFu) s += (s_st[lo] == 1) ? 1 : 0;
        if (hi != 0xFFFFu) s += (s_st[hi] == 1) ? 1 : 0;
      }
      if (s > 0) {  // adding 0 is a no-op: exactness unaffected
#pragma unroll
        for (int j = 0; j < PREW; ++j) {
          uint32_t lo = w[j] & 0xFFFFu, hi = w[j] >> 16;
          if (lo != 0xFFFFu) atomicAdd(&nv[lo], s);
          if (hi != 0xFFFFu) atomicAdd(&nv[hi], s);
        }
        for (int j = PREW; j < words; ++j) {
          uint32_t ww = wb[(size_t)j * EE];
          uint32_t lo = ww & 0xFFFFu, hi = ww >> 16;
          if (lo != 0xFFFFu) atomicAdd(&nv[lo], s);
          if (hi != 0xFFFFu) atomicAdd(&nv[hi], s);
        }
      }
    }
    bar_lds();  // nv complete (LDS ordering only; output stores keep draining)

    // node phase: advance p in regs, draw transitions, write output rows, zero nv
    float* po = out + (size_t)(t + 1) * ROW;
    float* so = out + S_OFF + (size_t)(t + 1) * ROW;
#pragma unroll
    for (int k = 0; k < NPT; ++k) {
      int n = tid + k * SIMT;
      if (n < NN) {
        int st = s_st[n];
        int v = nv[n];
        nv[n] = 0;  // zero for next step (protected by the trailing bar_lds)
        float s1 = (st == 1) ? 1.f : 0.f;
        float new_cases = __fmul_rn(bet[k], (float)v);
        float new_rec   = __fmul_rn(gam[k], s1);
        float q0 = fminf(1.f, fmaxf(0.f, __fsub_rn(p0[k], new_cases)));
        float q1 = fminf(1.f, fmaxf(0.f, __fsub_rn(__fadd_rn(p1[k], new_cases), new_rec)));
        float q2 = fminf(1.f, fmaxf(0.f, __fadd_rn(p2[k], new_rec)));
        p0[k] = q0; p1[k] = q1; p2[k] = q2;

        bool was_S  = (st == 0);
        bool was_I  = (st == 1);
        bool s_to_I = was_S && (u1r[k] < q1);
        bool i_event = was_I && (u1r[k] < q2);
        bool u2lt   = (u2r[k] < 0.5f);
        bool i_to_R = i_event && u2lt;
        bool i_to_S = i_event && !u2lt;
        bool new_S = (was_S && !s_to_I) || i_to_S;
        bool new_I = s_to_I || (was_I && !i_event);
        bool new_R = (!was_S && !was_I) || i_to_R;

        po[n * 3 + 0] = q0; po[n * 3 + 1] = q1; po[n * 3 + 2] = q2;
        so[n * 3 + 0] = new_S ? 1.f : 0.f;
        so[n * 3 + 1] = new_I ? 1.f : 0.f;
        so[n * 3 + 2] = new_R ? 1.f : 0.f;
        s_st[n] = new_I ? 1 : (new_S ? 0 : 2);
      }
    }
    bar_lds();  // s_st/nv stable before next edge phase
  }
}

extern "C" void kernel_launch(void* const* d_in, const int* in_sizes, int n_in,
                              void* d_out, int out_size, void* d_ws, size_t ws_size,
                              hipStream_t stream) {
  const float* x      = (const float*)d_in[0];
  const float* H      = (const float*)d_in[1];
  const float* beta   = (const float*)d_in[2];
  const float* gamma_ = (const float*)d_in[3];
  float* out = (float*)d_out;

  // key chain: key0 = jax.random.key(42) = (0,42); split(key,3) partitionable:
  // subkey i = threefry(key, (0,i)); carry = subkey 0.
  StepKeys keys;
  uint32_t key0 = 0u, key1 = 42u;
  for (int t = 0; t < TS; ++t) {
    uint32_t a0, b0, a1, b1, a2, b2;
    tf2x32(key0, key1, 0u, 0u, a0, b0);
    tf2x32(key0, key1, 0u, 1u, a1, b1);
    tf2x32(key0, key1, 0u, 2u, a2, b2);
    keys.k1a[t] = a1; keys.k1b[t] = b1; keys.k2a[t] = a2; keys.k2b[t] = b2;
    key0 = a0; key1 = b0;
  }

  // workspace layout (~5.2 MB)
  size_t off = 0;
  auto take = [&](size_t bytes) { size_t o = off; off += (bytes + 255) & ~(size_t)255; return o; };
  size_t o_ec = take((size_t)TS * EE * sizeof(int));
  size_t o_ew = take((size_t)TS * WPR * EE * sizeof(uint32_t));
  size_t o_u1 = take((size_t)TS * NN * sizeof(float));
  size_t o_u2 = take((size_t)TS * NN * sizeof(float));

  int*      edge_cnt   = (int*)((char*)d_ws + o_ec);
  uint32_t* edge_words = (uint32_t*)((char*)d_ws + o_ew);
  float*    u1         = (float*)((char*)d_ws + o_u1);
  float*    u2         = (float*)((char*)d_ws + o_u2);

  k_rand<<<dim3((NN + 255) / 256, TS), 256, 0, stream>>>(u1, u2, keys);
  k_scan<<<TS * EE, 256, 0, stream>>>(H, edge_cnt, edge_words);
  k_sim<<<1, SIMT, 0, stream>>>(out, x, edge_cnt, edge_words, u1, u2, beta, gamma_);
}